// Round 6
// baseline (449.784 us; speedup 1.0000x reference)
//
#include <hip/hip_runtime.h>

#define N_ROWS 131072
#define K_CODES 1024
#define D_DIM 128
// Quantization of the reference's fp32 |x|^2-offset arithmetic can reorder
// codes whose pre-quantized score gap is < 2*0.5ulp(~128)=3.2e-5; mfma
// scoring error ~3e-7. MARGIN = 5e-5 gives ~1.5x safety.
#define MARGIN 5.0e-5f
// Candidate window inside the full rescan (vs its own fp32 min, err ~3e-8).
#define CAND_MARGIN 4.0e-5f

typedef __attribute__((ext_vector_type(8)))  short short8;   // 8 bf16, 4 VGPRs
typedef __attribute__((ext_vector_type(4)))  float f32x4;

// ws layout (bytes) — total 1,589,248:
//   0       : unsigned work_count              (zeroed by vq_n2)
//   1024    : float  n2[K_CODES]               (4 KB)  np-pairwise-exact fp32
//   8192    : unsigned best_idx[N_ROWS]        (512 KB)
//   532480  : unsigned work_list[N_ROWS]       (512 KB)  row|i2<<17|full<<31
//   1056768 : double partials[1024]            (8 KB)
//   1064960 : ushort EH[K][D]                  (256 KB)  bf16 hi of -2*codebook
//   1327104 : ushort EL[K][D]                  (256 KB)  bf16 lo of -2*codebook

// ---- bf16 round-to-nearest-even split helpers ----
__device__ __forceinline__ unsigned short bf16_rn(float f) {
    unsigned u = __float_as_uint(f);
    unsigned r = u + 0x7fffu + ((u >> 16) & 1u);
    return (unsigned short)(r >> 16);
}
__device__ __forceinline__ float bf16_to_f(unsigned short h) {
    return __uint_as_float(((unsigned)h) << 16);
}

// numpy pairwise_sum (n=128) replica: 8 accumulators stride-8, then pairwise
// combine. __f*_rn blocks contraction so every op gets its own fp32 rounding.
__device__ __forceinline__ float np_sumsq_128(const float* __restrict__ p) {
    float r[8];
    #pragma unroll
    for (int j = 0; j < 8; ++j) r[j] = __fmul_rn(p[j], p[j]);
    #pragma unroll
    for (int i = 8; i < 128; i += 8)
        #pragma unroll
        for (int j = 0; j < 8; ++j)
            r[j] = __fadd_rn(r[j], __fmul_rn(p[i + j], p[i + j]));
    float t01 = __fadd_rn(r[0], r[1]), t23 = __fadd_rn(r[2], r[3]);
    float t45 = __fadd_rn(r[4], r[5]), t67 = __fadd_rn(r[6], r[7]);
    return __fadd_rn(__fadd_rn(t01, t23), __fadd_rn(t45, t67));
}

// fp32 score helper for the full-rescan path (self-consistent across passes).
__device__ __forceinline__ float score_f32(const float* __restrict__ e,
                                           const float* __restrict__ xr, float nn) {
    float a0 = 0.f, a1 = 0.f, a2 = 0.f, a3 = 0.f;
    #pragma unroll
    for (int d = 0; d < D_DIM; d += 4) {
        f32x4 ev = *(const f32x4*)(e + d);
        a0 = fmaf(xr[d + 0], ev.x, a0);
        a1 = fmaf(xr[d + 1], ev.y, a1);
        a2 = fmaf(xr[d + 2], ev.z, a2);
        a3 = fmaf(xr[d + 3], ev.w, a3);
    }
    return fmaf(-2.f, (a0 + a1) + (a2 + a3), nn);
}

// np-quantized score: d = fp32( fp32(A + B_c) - 2*fp32(fp64 x.e_c) ).
__device__ __forceinline__ float quant_score(const float* __restrict__ e,
                                             const float* __restrict__ xr,
                                             float A, float nn) {
    double dotd = 0.0;
    #pragma unroll
    for (int d = 0; d < D_DIM; ++d)
        dotd = fma((double)e[d], (double)xr[d], dotd);
    float M  = (float)dotd;              // one fp32 rounding (sgemm-like)
    float t1 = __fadd_rn(A, nn);         // fp32(A + B_c)
    return __fsub_rn(t1, 2.0f * M);      // 2M exact
}

// ---------------- kernel 1: codebook squared norms + counter init -----------
__global__ void vq_n2(const float* __restrict__ cb, float* __restrict__ n2,
                      unsigned* __restrict__ work_count) {
    if (blockIdx.x == 0 && threadIdx.x == 0) *work_count = 0;
    int code = blockIdx.x * 256 + threadIdx.x;   // grid = 4 blocks
    n2[code] = np_sumsq_128(cb + (size_t)code * D_DIM);
}

// ---------------- kernel 1b: split -2*codebook into bf16 hi/lo --------------
// -2x is exact in fp32, and bf16 rounding commutes with *2^k, so the split
// identity (-2e = EH + EL + tiny) holds exactly. Folding -2 here lets the
// MFMA accumulate the final score directly (acc init = n2).
__global__ void vq_split(const float* __restrict__ cb, unsigned short* __restrict__ EH,
                         unsigned short* __restrict__ EL) {
    int i = blockIdx.x * 256 + threadIdx.x;      // grid = 512 blocks
    float e = -2.0f * cb[i];
    unsigned short h = bf16_rn(e);
    float fl = e - bf16_to_f(h);                 // exact (Sterbenz)
    EH[i] = h;
    EL[i] = bf16_rn(fl);
}

// ---------------- kernel 2: MFMA scoring + per-row top-3 ----------------
// Codes on M, rows on N. C/D: col=lane&15 -> x-row (fixed per lane),
// row=quad*4+reg -> code. Each wave: 32 rows (2 tiles) x all 1024 codes.
// 1024 blocks -> 4 blocks/CU -> 4 waves/SIMD (needs VGPR <= 128).
// score = n2[c] + x.(-2e) via eh*xh + eh*xl + el*xh, acc init = n2.
__launch_bounds__(256, 4)
__global__ void vq_mfma(const float* __restrict__ x,
                        const unsigned short* __restrict__ EH,
                        const unsigned short* __restrict__ EL,
                        const float* __restrict__ n2,
                        unsigned* __restrict__ best_idx,
                        unsigned* __restrict__ work_list,
                        unsigned* __restrict__ work_count) {
    const int lane = threadIdx.x & 63;
    const int wid  = threadIdx.x >> 6;
    const int q    = lane >> 4;          // quad 0..3
    const int col  = lane & 15;
    const int rbase = blockIdx.x * 128 + wid * 32;

    // B operand (x rows), resident: B[k][n]: n = col = row-in-tile, k = q*8+j.
    short8 xh[2][4], xl[2][4];           // 64 VGPRs
    #pragma unroll
    for (int r = 0; r < 2; ++r) {
        const float* xrow = x + (size_t)(rbase + 16 * r + col) * D_DIM;
        #pragma unroll
        for (int k = 0; k < 4; ++k) {
            const float* p = xrow + k * 32 + q * 8;
            f32x4 v0 = *(const f32x4*)p;
            f32x4 v1 = *(const f32x4*)(p + 4);
            float f[8] = {v0.x, v0.y, v0.z, v0.w, v1.x, v1.y, v1.z, v1.w};
            short8 h, l;
            #pragma unroll
            for (int j = 0; j < 8; ++j) {
                unsigned short hb = bf16_rn(f[j]);
                float fl = f[j] - bf16_to_f(hb);
                h[j] = (short)hb;
                l[j] = (short)bf16_rn(fl);
            }
            xh[r][k] = h; xl[r][k] = l;
        }
    }

    float b1[2], b2[2], b3[2];
    unsigned i1[2], i2[2];               // lane-local index: ct*16+g (+4q later)
    #pragma unroll
    for (int r = 0; r < 2; ++r) {
        b1[r] = b2[r] = b3[r] = 3.0e38f;
        i1[r] = i2[r] = 0;
    }

    for (int ct = 0; ct < K_CODES / 16; ++ct) {
        const unsigned short* ph = EH + ((size_t)(ct * 16 + col)) * D_DIM + q * 8;
        const unsigned short* pl = EL + ((size_t)(ct * 16 + col)) * D_DIM + q * 8;

        f32x4 nn = *(const f32x4*)(n2 + ct * 16 + q * 4);
        f32x4 acc[2];
        acc[0] = nn; acc[1] = nn;        // score accumulates on top of |e|^2

        #pragma unroll
        for (int k = 0; k < 4; ++k) {
            short8 eh = *(const short8*)(ph + k * 32);
            short8 el = *(const short8*)(pl + k * 32);
            #pragma unroll
            for (int r = 0; r < 2; ++r) {
                acc[r] = __builtin_amdgcn_mfma_f32_16x16x32_bf16(eh, xh[r][k], acc[r], 0, 0, 0);
                acc[r] = __builtin_amdgcn_mfma_f32_16x16x32_bf16(eh, xl[r][k], acc[r], 0, 0, 0);
                acc[r] = __builtin_amdgcn_mfma_f32_16x16x32_bf16(el, xh[r][k], acc[r], 0, 0, 0);
            }
        }

        #pragma unroll
        for (int r = 0; r < 2; ++r) {
            #pragma unroll
            for (int g = 0; g < 4; ++g) {
                float s = acc[r][g];
                unsigned cl = (unsigned)(ct * 16 + g);      // scalar immediate
                bool lt1 = s < b1[r];
                bool lt2 = s < b2[r];
                float nb3 = __builtin_amdgcn_fmed3f(b2[r], b3[r], s);
                float nb2 = __builtin_amdgcn_fmed3f(b1[r], b2[r], s);
                float nb1 = fminf(b1[r], s);
                i2[r] = lt1 ? i1[r] : (lt2 ? cl : i2[r]);
                i1[r] = lt1 ? cl : i1[r];
                b3[r] = nb3; b2[r] = nb2; b1[r] = nb1;
            }
        }
    }

    // globalize indices, then merge sorted top-3 across the 4 quads
    #pragma unroll
    for (int r = 0; r < 2; ++r) {
        i1[r] += (unsigned)(q * 4);
        i2[r] += (unsigned)(q * 4);
        #pragma unroll
        for (int m = 16; m <= 32; m <<= 1) {
            float    oa1 = __shfl_xor(b1[r], m), oa2 = __shfl_xor(b2[r], m), oa3 = __shfl_xor(b3[r], m);
            unsigned oj1 = __shfl_xor(i1[r], m), oj2 = __shfl_xor(i2[r], m);
            bool t1 = (oa1 < b1[r]) || (oa1 == b1[r] && oj1 < i1[r]);
            float    m1 = t1 ? oa1 : b1[r];
            unsigned w1 = t1 ? oj1 : i1[r];
            float    ha = t1 ? b1[r] : b2[r];   unsigned iha = t1 ? i1[r] : i2[r];
            float    hb = t1 ? oa2   : oa1;     unsigned ihb = t1 ? oj2   : oj1;
            bool t2 = (hb < ha) || (hb == ha && ihb < iha);
            float    m2 = t2 ? hb : ha;
            unsigned w2 = t2 ? ihb : iha;
            float ha2 = t2 ? ha : (t1 ? b2[r] : b3[r]);
            float hb2 = t2 ? (t1 ? oa3 : oa2) : hb;
            float m3 = fminf(ha2, hb2);
            b1[r] = m1; i1[r] = w1; b2[r] = m2; i2[r] = w2; b3[r] = m3;
        }
        if (lane < 16) {
            int row = rbase + 16 * r + lane;
            best_idx[row] = i1[r];
            if (b2[r] - b1[r] < MARGIN) {
                bool full = (b3[r] - b1[r] < MARGIN);
                unsigned p = atomicAdd(work_count, 1u);
                work_list[p] = (unsigned)row | (i2[r] << 17) | (full ? 0x80000000u : 0u);
            }
        }
    }
}

// ---------------- kernel 3: resolve flagged rows (pair or full) -------------
// One wave per work-list entry. Pair entries: quantized tie is provably
// between i1 and i2 (third score >= MARGIN away) -> 2 exact evals.
// Full entries (rare): candidate-windowed rescan.
__launch_bounds__(256, 1)
__global__ void vq_resolve(const float* __restrict__ x, const float* __restrict__ cb,
                           const float* __restrict__ n2,
                           const unsigned* __restrict__ work_count,
                           const unsigned* __restrict__ work_list,
                           unsigned* __restrict__ best_idx) {
    const int lane = threadIdx.x & 63;
    const unsigned gw = blockIdx.x * 4 + (threadIdx.x >> 6);
    const unsigned n = *work_count;
    for (unsigned wi = gw; wi < n; wi += 2048) {
        const unsigned e = work_list[wi];
        const unsigned row = e & 0x1FFFFu;
        const float* xrow = x + (size_t)row * D_DIM;

        float xr[D_DIM];
        #pragma unroll
        for (int i = 0; i < D_DIM / 4; ++i) {
            f32x4 v = ((const f32x4*)xrow)[i];
            xr[4 * i + 0] = v.x; xr[4 * i + 1] = v.y;
            xr[4 * i + 2] = v.z; xr[4 * i + 3] = v.w;
        }
        float A = np_sumsq_128(xr);

        if (!(e & 0x80000000u)) {
            // pair resolve (all lanes redundant; lane 0 stores)
            unsigned c2 = (e >> 17) & 0x3FFu;
            unsigned c1 = best_idx[row];
            float dq1 = quant_score(cb + (size_t)c1 * D_DIM, xr, A, n2[c1]);
            float dq2 = quant_score(cb + (size_t)c2 * D_DIM, xr, A, n2[c2]);
            unsigned win = (dq2 < dq1 || (dq2 == dq1 && c2 < c1)) ? c2 : c1;
            if (lane == 0) best_idx[row] = win;
        } else {
            // full rescan: fp32 min, then quantized-exact on the window
            float smin = 3.0e38f;
            #pragma unroll 1
            for (int j = 0; j < K_CODES / 64; ++j) {
                unsigned c = (unsigned)lane * (K_CODES / 64) + j;
                smin = fminf(smin, score_f32(cb + (size_t)c * D_DIM, xr, n2[c]));
            }
            float b1w = smin;
            #pragma unroll
            for (int m = 1; m < 64; m <<= 1) b1w = fminf(b1w, __shfl_xor(b1w, m));

            float bestq = 3.0e38f; unsigned bi = 0xffffffffu;
            #pragma unroll 1
            for (int j = 0; j < K_CODES / 64; ++j) {
                unsigned c = (unsigned)lane * (K_CODES / 64) + j;
                float s = score_f32(cb + (size_t)c * D_DIM, xr, n2[c]);
                if (s < b1w + CAND_MARGIN) {
                    float dq = quant_score(cb + (size_t)c * D_DIM, xr, A, n2[c]);
                    if (dq < bestq) { bestq = dq; bi = c; }   // strict < = first idx
                }
            }
            #pragma unroll
            for (int m = 1; m < 64; m <<= 1) {
                float    ob = __shfl_xor(bestq, m);
                unsigned oi = __shfl_xor(bi, m);
                if (ob < bestq || (ob == bestq && oi < bi)) { bestq = ob; bi = oi; }
            }
            if (lane == 0) best_idx[row] = bi;
        }
    }
}

// ---------------- kernel 4: gather + straight-through + loss partials --------
__global__ void vq_out(const float* __restrict__ x, const float* __restrict__ cb,
                       const unsigned* __restrict__ best_idx, float* __restrict__ out,
                       double* __restrict__ partials) {
    const int t = threadIdx.x;
    const int rloc = t >> 5;
    const int q = t & 31;
    double lsum = 0.0;
    for (int it = 0; it < N_ROWS / (1024 * 8); ++it) {
        int row = it * (1024 * 8) + blockIdx.x * 8 + rloc;
        unsigned idx = best_idx[row];
        float4 xv = ((const float4*)x)[(size_t)row * 32 + q];
        float4 ev = ((const float4*)cb)[(size_t)idx * 32 + q];
        float dx = ev.x - xv.x, dy = ev.y - xv.y, dz = ev.z - xv.z, dw = ev.w - xv.w;
        float4 o;
        o.x = xv.x + dx; o.y = xv.y + dy; o.z = xv.z + dz; o.w = xv.w + dw;
        ((float4*)out)[(size_t)row * 32 + q] = o;
        lsum += (double)dx * dx + (double)dy * dy + (double)dz * dz + (double)dw * dw;
        if (q == 0) out[(size_t)N_ROWS * D_DIM + 1 + row] = (float)idx;
    }
    #pragma unroll
    for (int m = 32; m >= 1; m >>= 1) lsum += __shfl_xor(lsum, m);
    __shared__ double wsum[4];
    if ((t & 63) == 0) wsum[t >> 6] = lsum;
    __syncthreads();
    if (t == 0) partials[blockIdx.x] = wsum[0] + wsum[1] + wsum[2] + wsum[3];
}

// ---------------- kernel 5: finalize loss ----------------
__global__ void vq_fin(const double* __restrict__ partials, float* __restrict__ out) {
    int t = threadIdx.x;
    double s = partials[t] + partials[t + 256] + partials[t + 512] + partials[t + 768];
    #pragma unroll
    for (int m = 32; m >= 1; m >>= 1) s += __shfl_xor(s, m);
    __shared__ double wsum[4];
    if ((t & 63) == 0) wsum[t >> 6] = s;
    __syncthreads();
    if (t == 0) {
        double total = wsum[0] + wsum[1] + wsum[2] + wsum[3];
        out[(size_t)N_ROWS * D_DIM] = (float)(1.25 * total / ((double)N_ROWS * D_DIM));
    }
}

extern "C" void kernel_launch(void* const* d_in, const int* in_sizes, int n_in,
                              void* d_out, int out_size, void* d_ws, size_t ws_size,
                              hipStream_t stream) {
    const float* x  = (const float*)d_in[0];
    const float* cb = (const float*)d_in[1];
    float* out = (float*)d_out;
    char* ws = (char*)d_ws;

    unsigned*       work_count = (unsigned*)ws;
    float*          n2         = (float*)(ws + 1024);
    unsigned*       best_idx   = (unsigned*)(ws + 8192);
    unsigned*       work_list  = (unsigned*)(ws + 8192 + 524288);
    double*         partials   = (double*)(ws + 8192 + 2 * 524288);
    unsigned short* EH         = (unsigned short*)(ws + 1064960);
    unsigned short* EL         = (unsigned short*)(ws + 1327104);

    vq_n2     <<<K_CODES / 256, 256, 0, stream>>>(cb, n2, work_count);
    vq_split  <<<K_CODES * D_DIM / 256, 256, 0, stream>>>(cb, EH, EL);
    vq_mfma   <<<N_ROWS / 128, 256, 0, stream>>>(x, EH, EL, n2, best_idx, work_list, work_count);
    vq_resolve<<<512, 256, 0, stream>>>(x, cb, n2, work_count, work_list, best_idx);
    vq_out    <<<1024, 256, 0, stream>>>(x, cb, best_idx, out, partials);
    vq_fin    <<<1, 256, 0, stream>>>(partials, out);
}